// Round 7
// baseline (3515.784 us; speedup 1.0000x reference)
//
#include <hip/hip_runtime.h>
#include <hip/hip_bf16.h>

#define N_EVENT 10000
#define N_IOC   40000
#define N_NODES 50000
#define E_EDGES 800000
#define D_EV 768
#define D_IO 128
#define H 256
#define R 8
#define NBASES 8
#define NLAYERS 3
#define EDIM 16
#define LN_EPS 1e-5f

#define NKEY (N_NODES * R)
#define SCAN_CHUNK 2048
#define NCHUNK ((NKEY + SCAN_CHUNK - 1) / SCAN_CHUNK)
#define KPRE (R * H)                   // 2048
#define KTOT (R * H + H)               // 2304
#define NBEV32 ((N_EVENT + 31) / 32)   // 313
#define NBIO32 (N_IOC / 32)            // 1250
#define NBLK64 ((N_NODES + 63) / 64)   // 782

typedef __hip_bfloat16 bf16;
typedef __attribute__((ext_vector_type(8))) short bf16x8;
typedef __attribute__((ext_vector_type(4))) float f32x4;

__device__ __forceinline__ float us2f(unsigned short u) {
    union { unsigned int i; float f; } x; x.i = ((unsigned int)u) << 16; return x.f;
}

// ===================== edge presort (counting sort by dst*R+rel) =====================
__global__ __launch_bounds__(256) void hist_kernel(const int* __restrict__ ei, const int* __restrict__ et,
                                                   int* __restrict__ cnt) {
    int e = blockIdx.x * 256 + threadIdx.x;
    if (e < E_EDGES) atomicAdd(&cnt[ei[E_EDGES + e] * R + et[e]], 1);
}

__global__ __launch_bounds__(256) void scan1_kernel(const int* __restrict__ cnt, int* __restrict__ offs,
                                                    int* __restrict__ bsum) {
    __shared__ int s[256];
    int t = threadIdx.x;
    long base = (long)blockIdx.x * SCAN_CHUNK + t * 8;
    int v[8]; int sum = 0;
    #pragma unroll
    for (int i = 0; i < 8; ++i) { long idx = base + i; v[i] = (idx < NKEY) ? cnt[idx] : 0; sum += v[i]; }
    s[t] = sum; __syncthreads();
    for (int off = 1; off < 256; off <<= 1) {
        int x = (t >= off) ? s[t - off] : 0;
        __syncthreads();
        s[t] += x;
        __syncthreads();
    }
    int run = s[t] - sum;
    if (t == 255) bsum[blockIdx.x] = s[255];
    #pragma unroll
    for (int i = 0; i < 8; ++i) { long idx = base + i; if (idx < NKEY) offs[idx] = run; run += v[i]; }
}

__global__ __launch_bounds__(256) void scan2_kernel(int* __restrict__ bsum) {
    __shared__ int s[256];
    int t = threadIdx.x;
    int v = (t < NCHUNK) ? bsum[t] : 0;
    s[t] = v; __syncthreads();
    for (int off = 1; off < 256; off <<= 1) {
        int x = (t >= off) ? s[t - off] : 0;
        __syncthreads();
        s[t] += x;
        __syncthreads();
    }
    if (t < NCHUNK) bsum[t] = s[t] - v;
}

__global__ __launch_bounds__(256) void scan3_kernel(int* __restrict__ offs, const int* __restrict__ bsum) {
    int i = blockIdx.x * 256 + threadIdx.x;
    if (i < NKEY) offs[i] += bsum[i / SCAN_CHUNK];
    if (i == 0) offs[NKEY] = E_EDGES;
}

__global__ __launch_bounds__(256) void cinv_kernel(const int* __restrict__ cnt, float* __restrict__ cinv) {
    int i = blockIdx.x * 256 + threadIdx.x;
    if (i < NKEY) cinv[i] = 1.0f / (float)max(cnt[i], 1);
}

__global__ __launch_bounds__(256) void sort_kernel(const int* __restrict__ ei, const int* __restrict__ et,
                                                   const float* __restrict__ ew, const int* __restrict__ offs,
                                                   int* __restrict__ cnt, int* __restrict__ ssrc,
                                                   float* __restrict__ sew) {
    int e = blockIdx.x * 256 + threadIdx.x;
    if (e >= E_EDGES) return;
    int key = ei[E_EDGES + e] * R + et[e];
    int pos = offs[key] + atomicSub(&cnt[key], 1) - 1;
    ssrc[pos] = ei[e];
    sew[pos]  = ew[e];
}

// ===================== dtype prep =====================
__global__ __launch_bounds__(256) void cvt_x_kernel(const float* __restrict__ xev, const float* __restrict__ xio,
                                                    bf16* __restrict__ xevb, bf16* __restrict__ xiob) {
    const long NEV4 = (long)N_EVENT * D_EV / 4;
    const long NTOT4 = NEV4 + (long)N_IOC * D_IO / 4;
    long i = (long)blockIdx.x * 256 + threadIdx.x;
    if (i >= NTOT4) return;
    const float4* src; ushort4* dst; long j;
    if (i < NEV4) { src = (const float4*)xev; dst = (ushort4*)xevb; j = i; }
    else          { src = (const float4*)xio; dst = (ushort4*)xiob; j = i - NEV4; }
    float4 v = src[j];
    ushort4 o;
    bf16 a0 = __float2bfloat16(v.x), a1 = __float2bfloat16(v.y);
    bf16 a2 = __float2bfloat16(v.z), a3 = __float2bfloat16(v.w);
    o.x = *(unsigned short*)&a0; o.y = *(unsigned short*)&a1;
    o.z = *(unsigned short*)&a2; o.w = *(unsigned short*)&a3;
    dst[j] = o;
}

__global__ __launch_bounds__(256) void cvt_w_kernel(const float* __restrict__ wev, const float* __restrict__ wio,
                                                    bf16* __restrict__ wevT, bf16* __restrict__ wioT) {
    int n = blockIdx.x;
    for (int k = threadIdx.x; k < D_EV; k += 256)
        wevT[(size_t)n * D_EV + k] = __float2bfloat16(wev[(size_t)k * H + n]);
    for (int k = threadIdx.x; k < D_IO; k += 256)
        wioT[(size_t)n * D_IO + k] = __float2bfloat16(wio[(size_t)k * H + n]);
}

__global__ __launch_bounds__(256) void build_Bt_kernel(
    const float* __restrict__ bases, const float* __restrict__ comp, const float* __restrict__ root,
    bf16* __restrict__ Bt3) {
    int gb = blockIdx.x;
    int l = gb / KTOT, krow = gb % KTOT;
    int n = threadIdx.x;
    float v;
    if (krow < KPRE) {
        int r = krow >> 8, kk = krow & 255;
        v = 0.0f;
        const float* bs = bases + (size_t)l * NBASES * H * H + (size_t)kk * H + n;
        const float* cp = comp + (l * R + r) * NBASES;
        #pragma unroll
        for (int b = 0; b < NBASES; ++b) v += cp[b] * bs[(size_t)b * H * H];
    } else {
        int kk = krow - KPRE;
        v = root[((size_t)l * H + kk) * H + n];
    }
    Bt3[(size_t)l * H * KTOT + (size_t)n * KTOT + krow] = __float2bfloat16(v);
}

// ===================== edge-feature path =====================
__global__ __launch_bounds__(256) void edge_table_kernel(
    const float* __restrict__ emb, const float* __restrict__ mlp_w,
    const float* __restrict__ mlp_b, float* __restrict__ ctab, float* __restrict__ wlast) {
    int r = blockIdx.x, j = threadIdx.x;
    float acc = mlp_b[j];
    #pragma unroll
    for (int k = 0; k < EDIM; ++k) acc += emb[r * EDIM + k] * mlp_w[k * H + j];
    ctab[r * H + j] = acc;
    if (r == 0) wlast[j] = mlp_w[EDIM * H + j];
}

__global__ __launch_bounds__(256) void enh_bucket_kernel(
    const int* __restrict__ offs, const float* __restrict__ sew,
    const float* __restrict__ ctab, const float* __restrict__ wlast,
    bf16* __restrict__ enh) {
    __shared__ float ct[R * H];
    __shared__ float wl[H];
    for (int i = threadIdx.x; i < R * H; i += 256) ct[i] = ctab[i];
    for (int i = threadIdx.x; i < H; i += 256) wl[i] = wlast[i];
    __syncthreads();
    int w = threadIdx.x >> 6, lane = threadIdx.x & 63;
    int d = blockIdx.x * 4 + w;
    float acc[4] = {0.f, 0.f, 0.f, 0.f};
    int deg = offs[d * R + R] - offs[d * R];
    for (int r = 0; r < R; ++r) {
        int a = offs[d * R + r], b = offs[d * R + r + 1];
        for (int j = a; j < b; ++j) {
            float wt = sew[j];
            #pragma unroll
            for (int i = 0; i < 4; ++i) {
                int c = lane * 4 + i;
                acc[i] += fmaxf(ct[r * H + c] + wt * wl[c], 0.0f);
            }
        }
    }
    float inv = 1.0f / fmaxf((float)deg, 1.0f);
    unsigned short o[4];
    #pragma unroll
    for (int i = 0; i < 4; ++i) { bf16 hv = __float2bfloat16(acc[i] * inv); o[i] = *(unsigned short*)&hv; }
    *(ushort4*)(enh + (size_t)d * H + lane * 4) = *(ushort4*)o;
}

// ===================== fused layer kernel: gather + MFMA + LN + residual ==============
// One dispatch per layer. Block = 4 waves; wave = 16 dsts x 256 cols, zero barriers.
// A-fragment for K-chunk kc (relation r=kc>>3): lane (quad,m) gather-sums
// hb[src][ (kc*32&255) + quad*8 .. +8 ] over bucket(dst=row0+m, r), scales by cinv.
__global__ __launch_bounds__(256) void layer_kernel(
    const int* __restrict__ offs, const int* __restrict__ ssrc, const float* __restrict__ cinv,
    const bf16* __restrict__ hbR, const bf16* __restrict__ Bt, const bf16* __restrict__ enh,
    const float* __restrict__ bias, const float* __restrict__ gamma, const float* __restrict__ beta,
    bf16* __restrict__ hbW)
{
    int t = threadIdx.x, w = t >> 6, lane = t & 63;
    int quad = lane >> 4, m = lane & 15;
    int row0 = blockIdx.x * 64 + w * 16;
    int dst = row0 + m;
    int dstc = (dst < N_NODES) ? dst : (N_NODES - 1);

    f32x4 acc[16];
    #pragma unroll
    for (int c = 0; c < 16; ++c) { acc[c][0]=0.f; acc[c][1]=0.f; acc[c][2]=0.f; acc[c][3]=0.f; }

    const bf16* Bq = Bt + (size_t)m * KTOT;
    int bs = 0, be = 0; float sc = 0.f;

    // gather part: kc 0..63 (K = 8 relations x 256)
    for (int kc = 0; kc < 64; ++kc) {
        int k0 = kc * 32;
        if ((kc & 7) == 0) {
            int key = dstc * R + (kc >> 3);
            bs = offs[key]; be = offs[key + 1]; sc = cinv[key];
        }
        int coff = (k0 & 255) + quad * 8;
        float af[8] = {0.f,0.f,0.f,0.f,0.f,0.f,0.f,0.f};
        for (int j = bs; j < be; ++j) {
            int s = ssrc[j];
            bf16x8 hv = *(const bf16x8*)(hbR + (size_t)s * H + coff);
            #pragma unroll
            for (int i = 0; i < 8; ++i) af[i] += us2f((unsigned short)hv[i]);
        }
        bf16x8 a;
        #pragma unroll
        for (int i = 0; i < 8; ++i) {
            bf16 x = __float2bfloat16(af[i] * sc);
            a[i] = (short)*(unsigned short*)&x;
        }
        const bf16* bp = Bq + k0 + quad * 8;
        #pragma unroll
        for (int c = 0; c < 16; ++c) {
            bf16x8 b = *(const bf16x8*)(bp + (size_t)c * 16 * KTOT);
            acc[c] = __builtin_amdgcn_mfma_f32_16x16x32_bf16(a, b, acc[c], 0, 0, 0);
        }
    }
    // root part: kc 64..71, A = hb row direct
    {
        const bf16* Arow = hbR + (size_t)dstc * H;
        #pragma unroll
        for (int kc = 64; kc < 72; ++kc) {
            int k0 = kc * 32;
            bf16x8 a = *(const bf16x8*)(Arow + (k0 - KPRE) + quad * 8);
            const bf16* bp = Bq + k0 + quad * 8;
            #pragma unroll
            for (int c = 0; c < 16; ++c) {
                bf16x8 b = *(const bf16x8*)(bp + (size_t)c * 16 * KTOT);
                acc[c] = __builtin_amdgcn_mfma_f32_16x16x32_bf16(a, b, acc[c], 0, 0, 0);
            }
        }
    }

    // epilogue: wave-local LN over 256 cols (16 c-groups x 16 m-lanes), relu, residual
    float bv[16], gv[16], tv[16];
    #pragma unroll
    for (int c = 0; c < 16; ++c) {
        int col = c * 16 + m;
        bv[c] = bias[col]; gv[c] = gamma[col]; tv[c] = beta[col];
    }
    float s[4] = {0.f,0.f,0.f,0.f}, q[4] = {0.f,0.f,0.f,0.f};
    #pragma unroll
    for (int c = 0; c < 16; ++c) {
        #pragma unroll
        for (int i = 0; i < 4; ++i) {
            int row = row0 + quad * 4 + i;
            int rr = (row < N_NODES) ? row : (N_NODES - 1);
            int col = c * 16 + m;
            float e = us2f(*(const unsigned short*)(enh + (size_t)rr * H + col));
            float v = acc[c][i] + bv[c] + 0.1f * e;
            acc[c][i] = v;
            s[i] += v; q[i] += v * v;
        }
    }
    #pragma unroll
    for (int msk = 1; msk < 16; msk <<= 1) {
        #pragma unroll
        for (int i = 0; i < 4; ++i) { s[i] += __shfl_xor(s[i], msk); q[i] += __shfl_xor(q[i], msk); }
    }
    float mu[4], rs[4];
    #pragma unroll
    for (int i = 0; i < 4; ++i) {
        mu[i] = s[i] * (1.0f / H);
        rs[i] = rsqrtf(q[i] * (1.0f / H) - mu[i] * mu[i] + LN_EPS);
    }
    #pragma unroll
    for (int c = 0; c < 16; ++c) {
        #pragma unroll
        for (int i = 0; i < 4; ++i) {
            int row = row0 + quad * 4 + i;
            if (row < N_NODES) {
                size_t idx = (size_t)row * H + c * 16 + m;
                float y = (acc[c][i] - mu[i]) * rs[i] * gv[c] + tv[c];
                float hn = us2f(*(const unsigned short*)(hbR + idx)) + fmaxf(y, 0.0f);
                hbW[idx] = __float2bfloat16(hn);
            }
        }
    }
}

// ===================== col-split input projection GEMM + fused LN/ReLU =====================
__global__ __launch_bounds__(256) void proj3_kernel(
    const bf16* __restrict__ xevb, const bf16* __restrict__ xiob,
    const bf16* __restrict__ wevT, const bf16* __restrict__ wioT,
    const float* __restrict__ bev, const float* __restrict__ gev, const float* __restrict__ betev,
    const float* __restrict__ bio, const float* __restrict__ gio, const float* __restrict__ betio,
    bf16* __restrict__ hbW) {
    int t = threadIdx.x, w = t >> 6, lane = t & 63;
    int quad = lane >> 4, m = lane & 15;
    int blk = blockIdx.x;
    const bf16 *X, *WT; const float *bb, *gg, *be;
    int K, node0, x0, nvalid;
    if (blk < NBEV32) {
        X = xevb; WT = wevT; K = D_EV; x0 = blk * 32; node0 = x0;
        bb = bev; gg = gev; be = betev;
        nvalid = (N_EVENT - x0 < 32) ? (N_EVENT - x0) : 32;
    } else {
        int b2 = blk - NBEV32;
        X = xiob; WT = wioT; K = D_IO; x0 = b2 * 32; node0 = N_EVENT + x0;
        bb = bio; gg = gio; be = betio;
        nvalid = 32;
    }
    f32x4 acc0[4], acc1[4];
    #pragma unroll
    for (int c = 0; c < 4; ++c) {
        acc0[c][0]=0.f; acc0[c][1]=0.f; acc0[c][2]=0.f; acc0[c][3]=0.f;
        acc1[c][0]=0.f; acc1[c][1]=0.f; acc1[c][2]=0.f; acc1[c][3]=0.f;
    }
    int rA0 = m;      if (rA0 >= nvalid) rA0 = nvalid - 1;
    int rA1 = 16 + m; if (rA1 >= nvalid) rA1 = nvalid - 1;
    const bf16* A0 = X + (size_t)(x0 + rA0) * K;
    const bf16* A1 = X + (size_t)(x0 + rA1) * K;
    const bf16* Bbase = WT + (size_t)(w * 64 + m) * K;

    for (int kc = 0; kc < K / 32; ++kc) {
        int k0 = kc * 32;
        bf16x8 a0 = *(const bf16x8*)(A0 + k0 + quad * 8);
        bf16x8 a1 = *(const bf16x8*)(A1 + k0 + quad * 8);
        const bf16* bp = Bbase + k0 + quad * 8;
        #pragma unroll
        for (int c = 0; c < 4; ++c) {
            bf16x8 b = *(const bf16x8*)(bp + (size_t)c * 16 * K);
            acc0[c] = __builtin_amdgcn_mfma_f32_16x16x32_bf16(a0, b, acc0[c], 0, 0, 0);
            acc1[c] = __builtin_amdgcn_mfma_f32_16x16x32_bf16(a1, b, acc1[c], 0, 0, 0);
        }
    }

    float bv[4], gv[4], tv[4];
    #pragma unroll
    for (int c = 0; c < 4; ++c) {
        int col = w * 64 + c * 16 + m;
        bv[c] = bb[col]; gv[c] = gg[col]; tv[c] = be[col];
    }
    float s0[4]={0,0,0,0}, q0[4]={0,0,0,0}, s1[4]={0,0,0,0}, q1[4]={0,0,0,0};
    #pragma unroll
    for (int c = 0; c < 4; ++c) {
        #pragma unroll
        for (int i = 0; i < 4; ++i) {
            float v0 = acc0[c][i] + bv[c];
            float v1 = acc1[c][i] + bv[c];
            acc0[c][i] = v0; acc1[c][i] = v1;
            s0[i] += v0; q0[i] += v0 * v0;
            s1[i] += v1; q1[i] += v1 * v1;
        }
    }
    #pragma unroll
    for (int msk = 1; msk < 16; msk <<= 1) {
        #pragma unroll
        for (int i = 0; i < 4; ++i) {
            s0[i] += __shfl_xor(s0[i], msk); q0[i] += __shfl_xor(q0[i], msk);
            s1[i] += __shfl_xor(s1[i], msk); q1[i] += __shfl_xor(q1[i], msk);
        }
    }
    __shared__ float sred[4][32];
    __shared__ float qred[4][32];
    if (m == 0) {
        #pragma unroll
        for (int i = 0; i < 4; ++i) {
            sred[w][quad * 4 + i] = s0[i];      qred[w][quad * 4 + i] = q0[i];
            sred[w][16 + quad * 4 + i] = s1[i]; qred[w][16 + quad * 4 + i] = q1[i];
        }
    }
    __syncthreads();
    float mu0[4], rs0[4], mu1[4], rs1[4];
    #pragma unroll
    for (int i = 0; i < 4; ++i) {
        int rl0 = quad * 4 + i, rl1 = 16 + quad * 4 + i;
        float S0 = sred[0][rl0] + sred[1][rl0] + sred[2][rl0] + sred[3][rl0];
        float Q0 = qred[0][rl0] + qred[1][rl0] + qred[2][rl0] + qred[3][rl0];
        float S1 = sred[0][rl1] + sred[1][rl1] + sred[2][rl1] + sred[3][rl1];
        float Q1 = qred[0][rl1] + qred[1][rl1] + qred[2][rl1] + qred[3][rl1];
        mu0[i] = S0 * (1.0f / H);
        rs0[i] = rsqrtf(Q0 * (1.0f / H) - mu0[i] * mu0[i] + LN_EPS);
        mu1[i] = S1 * (1.0f / H);
        rs1[i] = rsqrtf(Q1 * (1.0f / H) - mu1[i] * mu1[i] + LN_EPS);
    }
    #pragma unroll
    for (int c = 0; c < 4; ++c) {
        #pragma unroll
        for (int i = 0; i < 4; ++i) {
            int col = w * 64 + c * 16 + m;
            int r0 = quad * 4 + i;
            if (r0 < nvalid) {
                float y = (acc0[c][i] - mu0[i]) * rs0[i] * gv[c] + tv[c];
                hbW[(size_t)(node0 + r0) * H + col] = __float2bfloat16(fmaxf(y, 0.0f));
            }
            int r1 = 16 + quad * 4 + i;
            if (r1 < nvalid) {
                float y = (acc1[c][i] - mu1[i]) * rs1[i] * gv[c] + tv[c];
                hbW[(size_t)(node0 + r1) * H + col] = __float2bfloat16(fmaxf(y, 0.0f));
            }
        }
    }
}

__global__ __launch_bounds__(256) void out_kernel(const bf16* __restrict__ hb, float* __restrict__ out) {
    size_t i = (size_t)blockIdx.x * 256 + threadIdx.x;
    if (i < (size_t)N_EVENT * H) out[i] = us2f(*(const unsigned short*)(hb + i));
}

extern "C" void kernel_launch(void* const* d_in, const int* in_sizes, int n_in,
                              void* d_out, int out_size, void* d_ws, size_t ws_size,
                              hipStream_t stream) {
    const float* xev   = (const float*)d_in[0];
    const float* xio   = (const float*)d_in[1];
    const int*   ei    = (const int*)d_in[2];
    const int*   et    = (const int*)d_in[3];
    const float* ew    = (const float*)d_in[4];
    const float* wev   = (const float*)d_in[5];
    const float* bev   = (const float*)d_in[6];
    const float* gev   = (const float*)d_in[7];
    const float* betev = (const float*)d_in[8];
    const float* wio   = (const float*)d_in[9];
    const float* bio   = (const float*)d_in[10];
    const float* gio   = (const float*)d_in[11];
    const float* betio = (const float*)d_in[12];
    const float* emb   = (const float*)d_in[13];
    const float* mlp_w = (const float*)d_in[14];
    const float* mlp_b = (const float*)d_in[15];
    const float* bases = (const float*)d_in[16];
    const float* comp  = (const float*)d_in[17];
    const float* root  = (const float*)d_in[18];
    const float* bias  = (const float*)d_in[19];
    const float* gamma = (const float*)d_in[20];
    const float* beta  = (const float*)d_in[21];

    char* base = (char*)d_ws;
    size_t o = 0;
    auto alloc = [&](size_t bytes) { char* p = base + o; o = (o + bytes + 255) & ~(size_t)255; return p; };
    bf16*  hbA  = (bf16*) alloc((size_t)N_NODES * H * 2);          // 25.6 MB
    bf16*  hbB  = (bf16*) alloc((size_t)N_NODES * H * 2);          // 25.6 MB
    bf16*  enh  = (bf16*) alloc((size_t)N_NODES * H * 2);          // 25.6 MB
    bf16*  xevb = (bf16*) alloc((size_t)N_EVENT * D_EV * 2);       // 15.4 MB
    bf16*  xiob = (bf16*) alloc((size_t)N_IOC * D_IO * 2);         // 10.2 MB
    bf16*  wevT = (bf16*) alloc((size_t)H * D_EV * 2);
    bf16*  wioT = (bf16*) alloc((size_t)H * D_IO * 2);
    bf16*  Bt3  = (bf16*) alloc((size_t)NLAYERS * H * KTOT * 2);   // 3.5 MB
    float* ctab = (float*)alloc(R * H * 4);
    float* wlast= (float*)alloc(H * 4);
    float* cinv = (float*)alloc((size_t)NKEY * 4);
    int*   bsum = (int*)  alloc(256 * 4);
    int*   cnt  = (int*)  alloc((size_t)NKEY * 4);
    int*   offs = (int*)  alloc((size_t)(NKEY + 4) * 4);
    int*   ssrc = (int*)  alloc((size_t)E_EDGES * 4);
    float* sew  = (float*)alloc((size_t)E_EDGES * 4);
    // ~118 MB total

    hipMemsetAsync(cnt, 0, (size_t)NKEY * sizeof(int), stream);

    // edge presort
    hist_kernel<<<(E_EDGES + 255) / 256, 256, 0, stream>>>(ei, et, cnt);
    scan1_kernel<<<NCHUNK, 256, 0, stream>>>(cnt, offs, bsum);
    scan2_kernel<<<1, 256, 0, stream>>>(bsum);
    scan3_kernel<<<(NKEY + 255) / 256, 256, 0, stream>>>(offs, bsum);
    cinv_kernel<<<(NKEY + 255) / 256, 256, 0, stream>>>(cnt, cinv);
    sort_kernel<<<(E_EDGES + 255) / 256, 256, 0, stream>>>(ei, et, ew, offs, cnt, ssrc, sew);

    // dtype prep
    cvt_x_kernel<<<12500, 256, 0, stream>>>(xev, xio, xevb, xiob);
    cvt_w_kernel<<<H, 256, 0, stream>>>(wev, wio, wevT, wioT);
    build_Bt_kernel<<<NLAYERS * KTOT, 256, 0, stream>>>(bases, comp, root, Bt3);

    // node features + edge-feature means
    proj3_kernel<<<NBEV32 + NBIO32, 256, 0, stream>>>(
        xevb, xiob, wevT, wioT, bev, gev, betev, bio, gio, betio, hbA);
    edge_table_kernel<<<R, 256, 0, stream>>>(emb, mlp_w, mlp_b, ctab, wlast);
    enh_bucket_kernel<<<N_NODES / 4, 256, 0, stream>>>(offs, sew, ctab, wlast, enh);

    for (int l = 0; l < NLAYERS; ++l) {
        bf16* hbR = (l & 1) ? hbB : hbA;
        bf16* hbW = (l & 1) ? hbA : hbB;
        layer_kernel<<<NBLK64, 256, 0, stream>>>(
            offs, ssrc, cinv, hbR, Bt3 + (size_t)l * H * KTOT, enh,
            bias + l * H, gamma + l * H, beta + l * H, hbW);
    }

    out_kernel<<<((size_t)N_EVENT * H + 255) / 256, 256, 0, stream>>>(hbB, (float*)d_out);
}

// Round 8
// 2115.172 us; speedup vs baseline: 1.6622x; 1.6622x over previous
//
#include <hip/hip_runtime.h>
#include <hip/hip_bf16.h>

#define N_EVENT 10000
#define N_IOC   40000
#define N_NODES 50000
#define E_EDGES 800000
#define D_EV 768
#define D_IO 128
#define H 256
#define R 8
#define NBASES 8
#define NLAYERS 3
#define EDIM 16
#define LN_EPS 1e-5f

#define NKEY (N_NODES * R)
#define SCAN_CHUNK 2048
#define NCHUNK ((NKEY + SCAN_CHUNK - 1) / SCAN_CHUNK)
#define KPRE (R * H)                   // 2048
#define KTOT (R * H + H)               // 2304 (8 relations + root, stacked output cols)
#define NBEV32 ((N_EVENT + 31) / 32)   // 313
#define NBIO32 (N_IOC / 32)            // 1250
#define NRT ((N_NODES + 63) / 64)      // 782 row tiles for zgemm

typedef __hip_bfloat16 bf16;
typedef __attribute__((ext_vector_type(8))) short bf16x8;
typedef __attribute__((ext_vector_type(4))) float f32x4;

__device__ __forceinline__ float us2f(unsigned short u) {
    union { unsigned int i; float f; } x; x.i = ((unsigned int)u) << 16; return x.f;
}
__device__ __forceinline__ unsigned short f2us(float f) {
    bf16 h = __float2bfloat16(f); return *(unsigned short*)&h;
}

// ===================== edge presort (counting sort by dst*R+rel) =====================
__global__ __launch_bounds__(256) void hist_kernel(const int* __restrict__ ei, const int* __restrict__ et,
                                                   int* __restrict__ cnt) {
    int e = blockIdx.x * 256 + threadIdx.x;
    if (e < E_EDGES) atomicAdd(&cnt[ei[E_EDGES + e] * R + et[e]], 1);
}

__global__ __launch_bounds__(256) void scan1_kernel(const int* __restrict__ cnt, int* __restrict__ offs,
                                                    int* __restrict__ bsum) {
    __shared__ int s[256];
    int t = threadIdx.x;
    long base = (long)blockIdx.x * SCAN_CHUNK + t * 8;
    int v[8]; int sum = 0;
    #pragma unroll
    for (int i = 0; i < 8; ++i) { long idx = base + i; v[i] = (idx < NKEY) ? cnt[idx] : 0; sum += v[i]; }
    s[t] = sum; __syncthreads();
    for (int off = 1; off < 256; off <<= 1) {
        int x = (t >= off) ? s[t - off] : 0;
        __syncthreads();
        s[t] += x;
        __syncthreads();
    }
    int run = s[t] - sum;
    if (t == 255) bsum[blockIdx.x] = s[255];
    #pragma unroll
    for (int i = 0; i < 8; ++i) { long idx = base + i; if (idx < NKEY) offs[idx] = run; run += v[i]; }
}

__global__ __launch_bounds__(256) void scan2_kernel(int* __restrict__ bsum) {
    __shared__ int s[256];
    int t = threadIdx.x;
    int v = (t < NCHUNK) ? bsum[t] : 0;
    s[t] = v; __syncthreads();
    for (int off = 1; off < 256; off <<= 1) {
        int x = (t >= off) ? s[t - off] : 0;
        __syncthreads();
        s[t] += x;
        __syncthreads();
    }
    if (t < NCHUNK) bsum[t] = s[t] - v;
}

__global__ __launch_bounds__(256) void scan3_kernel(int* __restrict__ offs, const int* __restrict__ bsum) {
    int i = blockIdx.x * 256 + threadIdx.x;
    if (i < NKEY) offs[i] += bsum[i / SCAN_CHUNK];
    if (i == 0) offs[NKEY] = E_EDGES;
}

__global__ __launch_bounds__(256) void cinv_kernel(const int* __restrict__ cnt, float* __restrict__ cinv) {
    int i = blockIdx.x * 256 + threadIdx.x;
    if (i < NKEY) cinv[i] = 1.0f / (float)max(cnt[i], 1);
}

__global__ __launch_bounds__(256) void sort_kernel(const int* __restrict__ ei, const int* __restrict__ et,
                                                   const float* __restrict__ ew, const int* __restrict__ offs,
                                                   int* __restrict__ cnt, int* __restrict__ ssrc,
                                                   float* __restrict__ sew) {
    int e = blockIdx.x * 256 + threadIdx.x;
    if (e >= E_EDGES) return;
    int key = ei[E_EDGES + e] * R + et[e];
    int pos = offs[key] + atomicSub(&cnt[key], 1) - 1;
    ssrc[pos] = ei[e];
    sew[pos]  = ew[e];
}

// ===================== dtype prep =====================
__global__ __launch_bounds__(256) void cvt_x_kernel(const float* __restrict__ xev, const float* __restrict__ xio,
                                                    bf16* __restrict__ xevb, bf16* __restrict__ xiob) {
    const long NEV4 = (long)N_EVENT * D_EV / 4;
    const long NTOT4 = NEV4 + (long)N_IOC * D_IO / 4;
    long i = (long)blockIdx.x * 256 + threadIdx.x;
    if (i >= NTOT4) return;
    const float4* src; ushort4* dst; long j;
    if (i < NEV4) { src = (const float4*)xev; dst = (ushort4*)xevb; j = i; }
    else          { src = (const float4*)xio; dst = (ushort4*)xiob; j = i - NEV4; }
    float4 v = src[j];
    ushort4 o;
    o.x = f2us(v.x); o.y = f2us(v.y); o.z = f2us(v.z); o.w = f2us(v.w);
    dst[j] = o;
}

__global__ __launch_bounds__(256) void cvt_w_kernel(const float* __restrict__ wev, const float* __restrict__ wio,
                                                    bf16* __restrict__ wevT, bf16* __restrict__ wioT) {
    int n = blockIdx.x;
    for (int k = threadIdx.x; k < D_EV; k += 256)
        wevT[(size_t)n * D_EV + k] = __float2bfloat16(wev[(size_t)k * H + n]);
    for (int k = threadIdx.x; k < D_IO; k += 256)
        wioT[(size_t)n * D_IO + k] = __float2bfloat16(wio[(size_t)k * H + n]);
}

// dense fp32 relation weights: Wtmp[l][rr][k][cc], rr=0..7 relations, rr=8 root
__global__ __launch_bounds__(256) void build_W_kernel(
    const float* __restrict__ bases, const float* __restrict__ comp, const float* __restrict__ root,
    float* __restrict__ Wtmp) {
    int gb = blockIdx.x;                 // (l*9+rr)*256 + k
    int k = gb & 255;
    int lr = gb >> 8;                    // l*9+rr
    int l = lr / 9, rr = lr % 9;
    int cc = threadIdx.x;
    float v;
    if (rr < 8) {
        v = 0.0f;
        const float* cp = comp + (l * R + rr) * NBASES;
        const float* bs = bases + ((size_t)l * NBASES * H + k) * H + cc;
        #pragma unroll
        for (int b = 0; b < NBASES; ++b) v += cp[b] * bs[(size_t)b * H * H];
    } else {
        v = root[((size_t)l * H + k) * H + cc];
    }
    Wtmp[(size_t)gb * H + cc] = v;
}

// transpose to bf16 Btn[l][j][k], j = rr*256+cc (output col), k = input 0..255
__global__ __launch_bounds__(256) void build_Btn_kernel(const float* __restrict__ Wtmp,
                                                        bf16* __restrict__ Btn) {
    int gb = blockIdx.x;                 // l*KTOT + j
    int l = gb / KTOT, j = gb % KTOT;
    int rr = j >> 8, cc = j & 255;
    int k = threadIdx.x;
    float v = Wtmp[(((size_t)(l * 9 + rr) * H) + k) * H + cc];
    Btn[(size_t)gb * H + k] = __float2bfloat16(v);
}

// ===================== edge-feature path =====================
__global__ __launch_bounds__(256) void edge_table_kernel(
    const float* __restrict__ emb, const float* __restrict__ mlp_w,
    const float* __restrict__ mlp_b, float* __restrict__ ctab, float* __restrict__ wlast) {
    int r = blockIdx.x, j = threadIdx.x;
    float acc = mlp_b[j];
    #pragma unroll
    for (int k = 0; k < EDIM; ++k) acc += emb[r * EDIM + k] * mlp_w[k * H + j];
    ctab[r * H + j] = acc;
    if (r == 0) wlast[j] = mlp_w[EDIM * H + j];
}

__global__ __launch_bounds__(256) void enh_bucket_kernel(
    const int* __restrict__ offs, const float* __restrict__ sew,
    const float* __restrict__ ctab, const float* __restrict__ wlast,
    bf16* __restrict__ enh) {
    __shared__ float ct[R * H];
    __shared__ float wl[H];
    for (int i = threadIdx.x; i < R * H; i += 256) ct[i] = ctab[i];
    for (int i = threadIdx.x; i < H; i += 256) wl[i] = wlast[i];
    __syncthreads();
    int w = threadIdx.x >> 6, lane = threadIdx.x & 63;
    int d = blockIdx.x * 4 + w;
    float acc[4] = {0.f, 0.f, 0.f, 0.f};
    int deg = offs[d * R + R] - offs[d * R];
    for (int r = 0; r < R; ++r) {
        int a = offs[d * R + r], b = offs[d * R + r + 1];
        for (int j = a; j < b; ++j) {
            float wt = sew[j];
            #pragma unroll
            for (int i = 0; i < 4; ++i) {
                int c = lane * 4 + i;
                acc[i] += fmaxf(ct[r * H + c] + wt * wl[c], 0.0f);
            }
        }
    }
    float inv = 1.0f / fmaxf((float)deg, 1.0f);
    unsigned short o[4];
    #pragma unroll
    for (int i = 0; i < 4; ++i) o[i] = f2us(acc[i] * inv);
    *(ushort4*)(enh + (size_t)d * H + lane * 4) = *(ushort4*)o;
}

// ===================== dense transform GEMM: Z[ct][n][c] = hb @ W_ct ==================
// grid = (c1-c0)*NRT blocks; consecutive blocks share a B col-tile (L2-hot).
__global__ __launch_bounds__(256) void zgemm_kernel(
    const bf16* __restrict__ hb, const bf16* __restrict__ Btl,
    bf16* __restrict__ Zbase, int ctbase) {
    int t = threadIdx.x, w = t >> 6, lane = t & 63;
    int quad = lane >> 4, m = lane & 15;
    int ctl = blockIdx.x / NRT;
    int rt  = blockIdx.x % NRT;
    int ct  = ctbase + ctl;
    int row0 = rt * 64 + w * 16;
    int rowA = row0 + m; if (rowA >= N_NODES) rowA = N_NODES - 1;
    const bf16* Ap = hb + (size_t)rowA * H;
    const bf16* Bp = Btl + ((size_t)ct * 256 + m) * H;   // + c*16*H + k
    f32x4 acc[16];
    #pragma unroll
    for (int c = 0; c < 16; ++c) { acc[c][0]=0.f; acc[c][1]=0.f; acc[c][2]=0.f; acc[c][3]=0.f; }
    #pragma unroll
    for (int kc = 0; kc < 8; ++kc) {
        bf16x8 a = *(const bf16x8*)(Ap + kc * 32 + quad * 8);
        const bf16* bp = Bp + kc * 32 + quad * 8;
        #pragma unroll
        for (int c = 0; c < 16; ++c) {
            bf16x8 b = *(const bf16x8*)(bp + (size_t)c * 16 * H);
            acc[c] = __builtin_amdgcn_mfma_f32_16x16x32_bf16(a, b, acc[c], 0, 0, 0);
        }
    }
    bf16* Zw = Zbase + (size_t)ctl * N_NODES * H;
    #pragma unroll
    for (int c = 0; c < 16; ++c) {
        #pragma unroll
        for (int i = 0; i < 4; ++i) {
            int row = row0 + quad * 4 + i;
            if (row < N_NODES) Zw[(size_t)row * H + c * 16 + m] = __float2bfloat16(acc[c][i]);
        }
    }
}

// ===================== coalesced gather + LN + residual =====================
// Wave = one dst. Per edge: one coalesced 512B row read of Z[r][src].
// flags: 1 = first pass (acc=0), 2 = last pass (finalize into hb in-place).
__global__ __launch_bounds__(256) void gather_kernel(
    const int* __restrict__ offs, const int* __restrict__ ssrc, const float* __restrict__ cinv,
    const bf16* __restrict__ Z, const bf16* __restrict__ enh,
    const float* __restrict__ bias, const float* __restrict__ gamma, const float* __restrict__ beta,
    bf16* __restrict__ hb, bf16* __restrict__ aggb, int c0, int c1, int flags) {
    int w = threadIdx.x >> 6, lane = threadIdx.x & 63;
    int d = blockIdx.x * 4 + w;
    const ushort4* Z4 = (const ushort4*)Z;
    float acc[4];
    if (flags & 1) { acc[0]=0.f; acc[1]=0.f; acc[2]=0.f; acc[3]=0.f; }
    else {
        ushort4 u = *(const ushort4*)(aggb + (size_t)d * H + lane * 4);
        acc[0]=us2f(u.x); acc[1]=us2f(u.y); acc[2]=us2f(u.z); acc[3]=us2f(u.w);
    }
    int rend = (c1 < 9) ? c1 : 8;
    for (int ctn = c0; ctn < rend; ++ctn) {
        int key = d * R + ctn;
        int a = offs[key], b = offs[key + 1];
        float sc = cinv[key];
        float rs[4] = {0.f, 0.f, 0.f, 0.f};
        size_t zoff = (size_t)(ctn - c0) * N_NODES * 64;
        int j = a;
        for (; j + 1 < b; j += 2) {
            int s0 = ssrc[j], s1 = ssrc[j + 1];
            ushort4 u0 = Z4[zoff + (size_t)s0 * 64 + lane];
            ushort4 u1 = Z4[zoff + (size_t)s1 * 64 + lane];
            rs[0] += us2f(u0.x) + us2f(u1.x);
            rs[1] += us2f(u0.y) + us2f(u1.y);
            rs[2] += us2f(u0.z) + us2f(u1.z);
            rs[3] += us2f(u0.w) + us2f(u1.w);
        }
        if (j < b) {
            int s0 = ssrc[j];
            ushort4 u0 = Z4[zoff + (size_t)s0 * 64 + lane];
            rs[0] += us2f(u0.x); rs[1] += us2f(u0.y); rs[2] += us2f(u0.z); rs[3] += us2f(u0.w);
        }
        #pragma unroll
        for (int i = 0; i < 4; ++i) acc[i] += sc * rs[i];
    }
    if (c1 == 9) {   // root block
        ushort4 u = Z4[(size_t)(8 - c0) * N_NODES * 64 + (size_t)d * 64 + lane];
        acc[0] += us2f(u.x); acc[1] += us2f(u.y); acc[2] += us2f(u.z); acc[3] += us2f(u.w);
    }
    if (flags & 2) {
        int col = lane * 4;
        ushort4 ue = *(const ushort4*)(enh + (size_t)d * H + col);
        float v[4];
        v[0] = acc[0] + bias[col+0] + 0.1f * us2f(ue.x);
        v[1] = acc[1] + bias[col+1] + 0.1f * us2f(ue.y);
        v[2] = acc[2] + bias[col+2] + 0.1f * us2f(ue.z);
        v[3] = acc[3] + bias[col+3] + 0.1f * us2f(ue.w);
        float s = v[0]+v[1]+v[2]+v[3];
        float q = v[0]*v[0]+v[1]*v[1]+v[2]*v[2]+v[3]*v[3];
        #pragma unroll
        for (int msk = 1; msk < 64; msk <<= 1) { s += __shfl_xor(s, msk); q += __shfl_xor(q, msk); }
        float mu = s * (1.0f / H);
        float rstd = rsqrtf(q * (1.0f / H) - mu * mu + LN_EPS);
        ushort4 uh = *(const ushort4*)(hb + (size_t)d * H + col);
        float h0 = us2f(uh.x), h1 = us2f(uh.y), h2 = us2f(uh.z), h3 = us2f(uh.w);
        unsigned short o[4];
        o[0] = f2us(h0 + fmaxf((v[0]-mu)*rstd*gamma[col+0] + beta[col+0], 0.0f));
        o[1] = f2us(h1 + fmaxf((v[1]-mu)*rstd*gamma[col+1] + beta[col+1], 0.0f));
        o[2] = f2us(h2 + fmaxf((v[2]-mu)*rstd*gamma[col+2] + beta[col+2], 0.0f));
        o[3] = f2us(h3 + fmaxf((v[3]-mu)*rstd*gamma[col+3] + beta[col+3], 0.0f));
        *(ushort4*)(hb + (size_t)d * H + col) = *(ushort4*)o;
    } else {
        unsigned short o[4];
        o[0]=f2us(acc[0]); o[1]=f2us(acc[1]); o[2]=f2us(acc[2]); o[3]=f2us(acc[3]);
        *(ushort4*)(aggb + (size_t)d * H + lane * 4) = *(ushort4*)o;
    }
}

// ===================== col-split input projection GEMM + fused LN/ReLU =====================
__global__ __launch_bounds__(256) void proj3_kernel(
    const bf16* __restrict__ xevb, const bf16* __restrict__ xiob,
    const bf16* __restrict__ wevT, const bf16* __restrict__ wioT,
    const float* __restrict__ bev, const float* __restrict__ gev, const float* __restrict__ betev,
    const float* __restrict__ bio, const float* __restrict__ gio, const float* __restrict__ betio,
    bf16* __restrict__ hbW) {
    int t = threadIdx.x, w = t >> 6, lane = t & 63;
    int quad = lane >> 4, m = lane & 15;
    int blk = blockIdx.x;
    const bf16 *X, *WT; const float *bb, *gg, *be;
    int K, node0, x0, nvalid;
    if (blk < NBEV32) {
        X = xevb; WT = wevT; K = D_EV; x0 = blk * 32; node0 = x0;
        bb = bev; gg = gev; be = betev;
        nvalid = (N_EVENT - x0 < 32) ? (N_EVENT - x0) : 32;
    } else {
        int b2 = blk - NBEV32;
        X = xiob; WT = wioT; K = D_IO; x0 = b2 * 32; node0 = N_EVENT + x0;
        bb = bio; gg = gio; be = betio;
        nvalid = 32;
    }
    f32x4 acc0[4], acc1[4];
    #pragma unroll
    for (int c = 0; c < 4; ++c) {
        acc0[c][0]=0.f; acc0[c][1]=0.f; acc0[c][2]=0.f; acc0[c][3]=0.f;
        acc1[c][0]=0.f; acc1[c][1]=0.f; acc1[c][2]=0.f; acc1[c][3]=0.f;
    }
    int rA0 = m;      if (rA0 >= nvalid) rA0 = nvalid - 1;
    int rA1 = 16 + m; if (rA1 >= nvalid) rA1 = nvalid - 1;
    const bf16* A0 = X + (size_t)(x0 + rA0) * K;
    const bf16* A1 = X + (size_t)(x0 + rA1) * K;
    const bf16* Bbase = WT + (size_t)(w * 64 + m) * K;

    for (int kc = 0; kc < K / 32; ++kc) {
        int k0 = kc * 32;
        bf16x8 a0 = *(const bf16x8*)(A0 + k0 + quad * 8);
        bf16x8 a1 = *(const bf16x8*)(A1 + k0 + quad * 8);
        const bf16* bp = Bbase + k0 + quad * 8;
        #pragma unroll
        for (int c = 0; c < 4; ++c) {
            bf16x8 b = *(const bf16x8*)(bp + (size_t)c * 16 * K);
            acc0[c] = __builtin_amdgcn_mfma_f32_16x16x32_bf16(a0, b, acc0[c], 0, 0, 0);
            acc1[c] = __builtin_amdgcn_mfma_f32_16x16x32_bf16(a1, b, acc1[c], 0, 0, 0);
        }
    }

    float bv[4], gv[4], tv[4];
    #pragma unroll
    for (int c = 0; c < 4; ++c) {
        int col = w * 64 + c * 16 + m;
        bv[c] = bb[col]; gv[c] = gg[col]; tv[c] = be[col];
    }
    float s0[4]={0,0,0,0}, q0[4]={0,0,0,0}, s1[4]={0,0,0,0}, q1[4]={0,0,0,0};
    #pragma unroll
    for (int c = 0; c < 4; ++c) {
        #pragma unroll
        for (int i = 0; i < 4; ++i) {
            float v0 = acc0[c][i] + bv[c];
            float v1 = acc1[c][i] + bv[c];
            acc0[c][i] = v0; acc1[c][i] = v1;
            s0[i] += v0; q0[i] += v0 * v0;
            s1[i] += v1; q1[i] += v1 * v1;
        }
    }
    #pragma unroll
    for (int msk = 1; msk < 16; msk <<= 1) {
        #pragma unroll
        for (int i = 0; i < 4; ++i) {
            s0[i] += __shfl_xor(s0[i], msk); q0[i] += __shfl_xor(q0[i], msk);
            s1[i] += __shfl_xor(s1[i], msk); q1[i] += __shfl_xor(q1[i], msk);
        }
    }
    __shared__ float sred[4][32];
    __shared__ float qred[4][32];
    if (m == 0) {
        #pragma unroll
        for (int i = 0; i < 4; ++i) {
            sred[w][quad * 4 + i] = s0[i];      qred[w][quad * 4 + i] = q0[i];
            sred[w][16 + quad * 4 + i] = s1[i]; qred[w][16 + quad * 4 + i] = q1[i];
        }
    }
    __syncthreads();
    float mu0[4], rs0[4], mu1[4], rs1[4];
    #pragma unroll
    for (int i = 0; i < 4; ++i) {
        int rl0 = quad * 4 + i, rl1 = 16 + quad * 4 + i;
        float S0 = sred[0][rl0] + sred[1][rl0] + sred[2][rl0] + sred[3][rl0];
        float Q0 = qred[0][rl0] + qred[1][rl0] + qred[2][rl0] + qred[3][rl0];
        float S1 = sred[0][rl1] + sred[1][rl1] + sred[2][rl1] + sred[3][rl1];
        float Q1 = qred[0][rl1] + qred[1][rl1] + qred[2][rl1] + qred[3][rl1];
        mu0[i] = S0 * (1.0f / H);
        rs0[i] = rsqrtf(Q0 * (1.0f / H) - mu0[i] * mu0[i] + LN_EPS);
        mu1[i] = S1 * (1.0f / H);
        rs1[i] = rsqrtf(Q1 * (1.0f / H) - mu1[i] * mu1[i] + LN_EPS);
    }
    #pragma unroll
    for (int c = 0; c < 4; ++c) {
        #pragma unroll
        for (int i = 0; i < 4; ++i) {
            int col = w * 64 + c * 16 + m;
            int r0 = quad * 4 + i;
            if (r0 < nvalid) {
                float y = (acc0[c][i] - mu0[i]) * rs0[i] * gv[c] + tv[c];
                hbW[(size_t)(node0 + r0) * H + col] = __float2bfloat16(fmaxf(y, 0.0f));
            }
            int r1 = 16 + quad * 4 + i;
            if (r1 < nvalid) {
                float y = (acc1[c][i] - mu1[i]) * rs1[i] * gv[c] + tv[c];
                hbW[(size_t)(node0 + r1) * H + col] = __float2bfloat16(fmaxf(y, 0.0f));
            }
        }
    }
}

__global__ __launch_bounds__(256) void out_kernel(const bf16* __restrict__ hb, float* __restrict__ out) {
    size_t i = (size_t)blockIdx.x * 256 + threadIdx.x;
    if (i < (size_t)N_EVENT * H) out[i] = us2f(*(const unsigned short*)(hb + i));
}

extern "C" void kernel_launch(void* const* d_in, const int* in_sizes, int n_in,
                              void* d_out, int out_size, void* d_ws, size_t ws_size,
                              hipStream_t stream) {
    const float* xev   = (const float*)d_in[0];
    const float* xio   = (const float*)d_in[1];
    const int*   ei    = (const int*)d_in[2];
    const int*   et    = (const int*)d_in[3];
    const float* ew    = (const float*)d_in[4];
    const float* wev   = (const float*)d_in[5];
    const float* bev   = (const float*)d_in[6];
    const float* gev   = (const float*)d_in[7];
    const float* betev = (const float*)d_in[8];
    const float* wio   = (const float*)d_in[9];
    const float* bio   = (const float*)d_in[10];
    const float* gio   = (const float*)d_in[11];
    const float* betio = (const float*)d_in[12];
    const float* emb   = (const float*)d_in[13];
    const float* mlp_w = (const float*)d_in[14];
    const float* mlp_b = (const float*)d_in[15];
    const float* bases = (const float*)d_in[16];
    const float* comp  = (const float*)d_in[17];
    const float* root  = (const float*)d_in[18];
    const float* bias  = (const float*)d_in[19];
    const float* gamma = (const float*)d_in[20];
    const float* beta  = (const float*)d_in[21];

    char* base = (char*)d_ws;
    size_t o = 0;
    auto alloc = [&](size_t bytes) { char* p = base + o; o = (o + bytes + 255) & ~(size_t)255; return p; };
    bf16*  hb   = (bf16*) alloc((size_t)N_NODES * H * 2);          // 25.6 MB (in-place activations)
    bf16*  enh  = (bf16*) alloc((size_t)N_NODES * H * 2);          // 25.6 MB
    bf16*  aggb = (bf16*) alloc((size_t)N_NODES * H * 2);          // 25.6 MB (multi-pass carry)
    bf16*  wevT = (bf16*) alloc((size_t)H * D_EV * 2);
    bf16*  wioT = (bf16*) alloc((size_t)H * D_IO * 2);
    bf16*  Btn  = (bf16*) alloc((size_t)NLAYERS * KTOT * H * 2);   // 3.5 MB [l][j][k]
    float* ctab = (float*)alloc(R * H * 4);
    float* wlast= (float*)alloc(H * 4);
    float* cinv = (float*)alloc((size_t)NKEY * 4);
    int*   bsum = (int*)  alloc(256 * 4);
    int*   cnt  = (int*)  alloc((size_t)NKEY * 4);
    int*   offs = (int*)  alloc((size_t)(NKEY + 4) * 4);
    int*   ssrc = (int*)  alloc((size_t)E_EDGES * 4);
    float* sew  = (float*)alloc((size_t)E_EDGES * 4);
    // Z region = remainder; preamble-only buffers union into its start
    size_t zoff = o;
    bf16*  Z    = (bf16*)(base + zoff);
    bf16*  xevb = (bf16*)(base + zoff);
    bf16*  xiob = (bf16*)(base + zoff + (size_t)N_EVENT * D_EV * 2);
    float* Wtmp = (float*)(base + ((zoff + (size_t)N_EVENT*D_EV*2 + (size_t)N_IOC*D_IO*2 + 255) & ~(size_t)255));

    size_t slab_bytes = (size_t)N_NODES * H * 2;     // 25.6 MB
    size_t zavail = (ws_size > zoff) ? (ws_size - zoff) : slab_bytes;
    int nslab = (int)(zavail / slab_bytes);
    if (nslab > 9) nslab = 9;
    if (nslab < 1) nslab = 1;

    hipMemsetAsync(cnt, 0, (size_t)NKEY * sizeof(int), stream);

    // edge presort
    hist_kernel<<<(E_EDGES + 255) / 256, 256, 0, stream>>>(ei, et, cnt);
    scan1_kernel<<<NCHUNK, 256, 0, stream>>>(cnt, offs, bsum);
    scan2_kernel<<<1, 256, 0, stream>>>(bsum);
    scan3_kernel<<<(NKEY + 255) / 256, 256, 0, stream>>>(offs, bsum);
    cinv_kernel<<<(NKEY + 255) / 256, 256, 0, stream>>>(cnt, cinv);
    sort_kernel<<<(E_EDGES + 255) / 256, 256, 0, stream>>>(ei, et, ew, offs, cnt, ssrc, sew);

    // dtype prep + weights
    cvt_x_kernel<<<12500, 256, 0, stream>>>(xev, xio, xevb, xiob);
    cvt_w_kernel<<<H, 256, 0, stream>>>(wev, wio, wevT, wioT);
    build_W_kernel<<<NLAYERS * 9 * H, 256, 0, stream>>>(bases, comp, root, Wtmp);
    build_Btn_kernel<<<NLAYERS * KTOT, 256, 0, stream>>>(Wtmp, Btn);

    // node features + edge-feature means
    proj3_kernel<<<NBEV32 + NBIO32, 256, 0, stream>>>(
        xevb, xiob, wevT, wioT, bev, gev, betev, bio, gio, betio, hb);
    edge_table_kernel<<<R, 256, 0, stream>>>(emb, mlp_w, mlp_b, ctab, wlast);
    enh_bucket_kernel<<<N_NODES / 4, 256, 0, stream>>>(offs, sew, ctab, wlast, enh);

    for (int l = 0; l < NLAYERS; ++l) {
        const bf16* Btl = Btn + (size_t)l * KTOT * H;
        int c0 = 0;
        while (c0 < 9) {
            int c1 = c0 + nslab; if (c1 > 9) c1 = 9;
            zgemm_kernel<<<(c1 - c0) * NRT, 256, 0, stream>>>(hb, Btl, Z, c0);
            int flags = (c0 == 0 ? 1 : 0) | (c1 == 9 ? 2 : 0);
            gather_kernel<<<N_NODES / 4, 256, 0, stream>>>(
                offs, ssrc, cinv, Z, enh, bias + l * H, gamma + l * H, beta + l * H,
                hb, aggb, c0, c1, flags);
            c0 = c1;
        }
    }

    out_kernel<<<((size_t)N_EVENT * H + 255) / 256, 256, 0, stream>>>(hb, (float*)d_out);
}